// Round 9
// baseline (118.764 us; speedup 1.0000x reference)
//
#include <hip/hip_runtime.h>
#include <hip/hip_bf16.h>

#define HOURS 24
#define NB 32
#define MM 128
#define EE 128

typedef short bf16x8 __attribute__((ext_vector_type(8)));
typedef float f32x4 __attribute__((ext_vector_type(4)));

__device__ __forceinline__ unsigned short f2bfu(float f) {
    __hip_bfloat16 h = __float2bfloat16(f);
    return __builtin_bit_cast(unsigned short, h);
}
__device__ __forceinline__ unsigned int pack2(float a, float b) {
    return (unsigned int)f2bfu(a) | ((unsigned int)f2bfu(b) << 16);
}
// swizzled short-index of 16B unit `unit` in row `row` of a [*][128] bf16 tile
__device__ __forceinline__ int swz8(int row, int unit) {
    return row * 128 + (((unit ^ (row & 7)) & 15) << 3);
}
// load 8 consecutive f32 from global, convert to bf16x8 fragment
__device__ __forceinline__ bf16x8 load_w_frag(const float* base) {
    float4 x = *(const float4*)base;
    float4 y = *(const float4*)(base + 4);
    union { unsigned int u[4]; bf16x8 v; } r;
    r.u[0] = pack2(x.x, x.y); r.u[1] = pack2(x.z, x.w);
    r.u[2] = pack2(y.x, y.y); r.u[3] = pack2(y.z, y.w);
    return r.v;
}

#define MFMA(a, b, c) __builtin_amdgcn_mfma_f32_16x16x32_bf16(a, b, c, 0, 0, 0)

// ws layout (shorts): qws | kws | vtws | saws each NB*MM*EE, then flags (ints)
#define WS_FLAGS_OFF ((size_t)4 * NB * MM * EE)   // in shorts
#define FLAG_STRIDE 32                            // ints (128B) per batch per stage

// ONE main kernel: 256 blocks = 32 batches x 8 chunks, 256 thr (4 waves).
// Stage 1: gather J stripe + stripe GEMMs (Q,K rows / VT cols) -> ws, flag1++
// Stage 2: wait flag1==8 -> 16-row attention chunk -> sa stripe -> ws, flag2++
// Stage 3: wait flag2==8 -> 16-candidate final contraction -> direct store
__global__ __launch_bounds__(256) void k_all(
    const int* __restrict__ full_seq, const int* __restrict__ time_seq,
    const int* __restrict__ user, const int* __restrict__ posneg,
    const int* __restrict__ traj_len,
    const float* __restrict__ mat1, const float* __restrict__ mat2,
    const float* __restrict__ vecg,
    const float* __restrict__ emb_t, const float* __restrict__ emb_u,
    const float* __restrict__ emb_loc,
    const float* __restrict__ esl, const float* __restrict__ esu,
    const float* __restrict__ etl, const float* __restrict__ etu,
    const float* __restrict__ Wq, const float* __restrict__ Wk,
    const float* __restrict__ Wv,
    short* __restrict__ ws, int* __restrict__ flags,
    float* __restrict__ outp)
{
    __shared__ alignas(16) short Jl[16 * 128];    // 4KB
    __shared__ alignas(16) float Sf[16 * 132];    // 8448B
    __shared__ alignas(16) short Pl[16 * 128];    // 4KB
    __shared__ float coef[8], tms[128], bsv[128];
    __shared__ float PART[4][16];

    short* qws  = ws;
    short* kws  = ws + (size_t)NB * MM * EE;
    short* vtws = ws + (size_t)2 * NB * MM * EE;
    short* saws = ws + (size_t)3 * NB * MM * EE;

    const int b = blockIdx.y;
    const int c = blockIdx.x;            // chunk 0..7
    const int m0 = c * 16;
    const int tid = threadIdx.x;
    const int w = tid >> 6, l = tid & 63;
    const int lr = l & 15, lg = l >> 4;
    const int tl = traj_len[b];
    int* flag1 = &flags[b * FLAG_STRIDE];
    int* flag2 = &flags[(NB + b) * FLAG_STRIDE];

    // ---- coefs: wave w computes coef[2w], coef[2w+1] ----
    {
        const float* tb4[4] = {esl, esu, etl, etu};
#pragma unroll
        for (int s = 0; s < 2; ++s) {
            int cc = 2 * w + s;
            const float* t = tb4[cc >> 1];
            float v = t[(cc & 1) * 128 + l] + t[(cc & 1) * 128 + 64 + l];
#pragma unroll
            for (int off = 32; off >= 1; off >>= 1) v += __shfl_xor(v, off, 64);
            if (l == 0) coef[cc] = v;
        }
    }
    // ---- gather J stripe (rows m0..m0+15), 1 idx pair per thread, high ILP ----
    {
        int row = tid >> 4;
        int m = m0 + row;
        int t = time_seq[b * MM + m];
        int tim = (t - 1) % HOURS + 1;
        int loc = full_seq[b * MM + m];
        int uid = user[b];
        const float4* Et4 = (const float4*)(emb_t + (size_t)tim * 128);
        const float4* El4 = (const float4*)(emb_loc + (size_t)loc * 128);
        const float4* Eu4 = (const float4*)(emb_u + (size_t)uid * 128);
#pragma unroll
        for (int it = 0; it < 2; ++it) {
            int fq = (tid & 15) * 2 + it;
            float4 a = Et4[fq], cc = El4[fq], u = Eu4[fq];
            uint2 pk;
            pk.x = pack2(a.x + cc.x + u.x, a.y + cc.y + u.y);
            pk.y = pack2(a.z + cc.z + u.z, a.w + cc.w + u.w);
            *(uint2*)&Jl[swz8(row, fq >> 1) + (fq & 1) * 4] = pk;
        }
    }
    __syncthreads();

    // ---- tms/bsv for all 128 m (needs coef) ----
    if (tid < 128) {
        int vv = (tid < tl) ? 1 : 0;
        float ssl = vv ? coef[1] : coef[0];
        float ssu = vv ? coef[3] : coef[2];
        float stl = vv ? coef[5] : coef[4];
        float stu = vv ? coef[7] : coef[6];
        tms[tid] = ssl + stl + (stu - stl) * 0.01f * vecg[b * MM + tid];
        bsv[tid] = (ssu - ssl) * 0.01f;
    }

    // ---- Stage 1: stripe GEMMs. J frags once; Q,K (D[n][m]) and VT (D[m][n]) ----
    {
        bf16x8 bj[4];
#pragma unroll
        for (int kf = 0; kf < 4; ++kf)
            bj[kf] = *(const bf16x8*)&Jl[swz8(lr, kf * 4 + lg)];
        // Q and K rows m0..m0+15, all 128 n; wave w: n-tiles {2w, 2w+1}
#pragma unroll
        for (int g = 0; g < 2; ++g) {
            const float* W = g ? Wk : Wq;
            short* outw = g ? kws : qws;
#pragma unroll
            for (int nt2 = 0; nt2 < 2; ++nt2) {
                int n = (2 * w + nt2) * 16 + lr;
                f32x4 acc = (f32x4){0.f, 0.f, 0.f, 0.f};
#pragma unroll
                for (int kf = 0; kf < 4; ++kf) {
                    bf16x8 af = load_w_frag(W + (size_t)n * 128 + kf * 32 + lg * 8);
                    acc = MFMA(af, bj[kf], acc);
                }
                int mg = m0 + lr;
                int n0 = (2 * w + nt2) * 16 + lg * 4;
                uint2 pk;
                pk.x = pack2(acc[0], acc[1]);
                pk.y = pack2(acc[2], acc[3]);
                *(uint2*)&outw[(size_t)(b * MM + mg) * EE + n0] = pk;
            }
        }
        // VT: D[m][n] = J . Wv^T -> vt[n][m0+lg*4..+3]
#pragma unroll
        for (int nt2 = 0; nt2 < 2; ++nt2) {
            int n = (2 * w + nt2) * 16 + lr;
            f32x4 acc = (f32x4){0.f, 0.f, 0.f, 0.f};
#pragma unroll
            for (int kf = 0; kf < 4; ++kf) {
                bf16x8 bw = load_w_frag(Wv + (size_t)n * 128 + kf * 32 + lg * 8);
                acc = MFMA(bj[kf], bw, acc);
            }
            int ng = (2 * w + nt2) * 16 + lr;
            int mp = m0 + lg * 4;
            uint2 pk;
            pk.x = pack2(acc[0], acc[1]);
            pk.y = pack2(acc[2], acc[3]);
            *(uint2*)&vtws[(size_t)(b * MM + ng) * MM + mp] = pk;
        }
    }
    __syncthreads();
    __threadfence();
    if (tid == 0)
        __hip_atomic_fetch_add(flag1, 1, __ATOMIC_RELEASE, __HIP_MEMORY_SCOPE_AGENT);
    // ---- wait for all 8 stripes of this batch ----
    if (tid == 0) {
        int guard = 0;
        while (__hip_atomic_load(flag1, __ATOMIC_ACQUIRE, __HIP_MEMORY_SCOPE_AGENT) < 8
               && guard < 100000000) { __builtin_amdgcn_s_sleep(2); ++guard; }
    }
    __syncthreads();
    __threadfence();

    // ---- Stage 2: attention for i-chunk c (rows m0..m0+15) ----
    {
        bf16x8 qf[4];
#pragma unroll
        for (int kf = 0; kf < 4; ++kf)
            qf[kf] = *(const bf16x8*)&qws[(size_t)(b * MM + m0 + lr) * EE + kf * 32 + lg * 8];
#pragma unroll
        for (int t2 = 0; t2 < 2; ++t2) {
            int jt = 2 * w + t2;
            f32x4 acc = (f32x4){0.f, 0.f, 0.f, 0.f};
#pragma unroll
            for (int kf = 0; kf < 4; ++kf) {
                bf16x8 bf = *(const bf16x8*)&kws[(size_t)(b * MM + jt * 16 + lr) * EE + kf * 32 + lg * 8];
                acc = MFMA(qf[kf], bf, acc);
            }
#pragma unroll
            for (int r = 0; r < 4; ++r)
                Sf[(lg * 4 + r) * 132 + jt * 16 + lr] = acc[r];
        }
    }
    __syncthreads();
    {
        int r16 = tid >> 4, u = tid & 15;
        int j0 = u * 8;
        int i = m0 + r16;
        int mi = (i < tl) ? 1 : 0;
        float c0_1 = coef[1] + coef[5];
        float c1_1 = (coef[3] - coef[1]) * 0.01f;
        float c2_1 = (coef[7] - coef[5]) * 0.01f;
        float c0_0 = coef[0] + coef[4];
        float c1_0 = (coef[2] - coef[0]) * 0.01f;
        float c2_0 = (coef[6] - coef[4]) * 0.01f;
        const float* sb = &Sf[r16 * 132 + j0];
        float4 s01 = *(const float4*)sb;
        float4 s23 = *(const float4*)(sb + 4);
        float sv[8] = {s01.x, s01.y, s01.z, s01.w, s23.x, s23.y, s23.z, s23.w};
        const float4* m14 = (const float4*)(mat1 + ((size_t)(b * MM + i) * MM + j0) * 2);
        float4 d0 = m14[0], d1 = m14[1], d2 = m14[2], d3 = m14[3];
        float ds[8] = {d0.x, d0.z, d1.x, d1.z, d2.x, d2.z, d3.x, d3.z};
        float dt[8] = {d0.y, d0.w, d1.y, d1.w, d2.y, d2.w, d3.y, d3.w};
        float lgv[8];
        int mk[8];
#pragma unroll
        for (int jj = 0; jj < 8; ++jj) {
            int j = j0 + jj;
            mk[jj] = mi & ((j < tl) ? 1 : 0);
            float cc0 = mk[jj] ? c0_1 : c0_0;
            float cc1 = mk[jj] ? c1_1 : c1_0;
            float cc2 = mk[jj] ? c2_1 : c2_0;
            lgv[jj] = sv[jj] + cc0 + cc1 * ds[jj] + cc2 * dt[jj];
        }
        float mx = lgv[0];
#pragma unroll
        for (int jj = 1; jj < 8; ++jj) mx = fmaxf(mx, lgv[jj]);
#pragma unroll
        for (int off = 8; off >= 1; off >>= 1) mx = fmaxf(mx, __shfl_xor(mx, off, 64));
        float ee[8], sum = 0.f;
#pragma unroll
        for (int jj = 0; jj < 8; ++jj) { ee[jj] = __expf(lgv[jj] - mx); sum += ee[jj]; }
#pragma unroll
        for (int off = 8; off >= 1; off >>= 1) sum += __shfl_xor(sum, off, 64);
        float inv = 1.0f / sum;
        uint4 pk;
        pk.x = pack2(ee[0] * inv * mk[0], ee[1] * inv * mk[1]);
        pk.y = pack2(ee[2] * inv * mk[2], ee[3] * inv * mk[3]);
        pk.z = pack2(ee[4] * inv * mk[4], ee[5] * inv * mk[5]);
        pk.w = pack2(ee[6] * inv * mk[6], ee[7] * inv * mk[7]);
        *(uint4*)&Pl[swz8(r16, u)] = pk;
    }
    __syncthreads();
    {
        bf16x8 bp[4];
#pragma unroll
        for (int kf = 0; kf < 4; ++kf)
            bp[kf] = *(const bf16x8*)&Pl[swz8(lr, kf * 4 + lg)];
#pragma unroll
        for (int t2 = 0; t2 < 2; ++t2) {
            int et = 2 * w + t2;
            f32x4 acc = (f32x4){0.f, 0.f, 0.f, 0.f};
#pragma unroll
            for (int kf = 0; kf < 4; ++kf) {
                bf16x8 af = *(const bf16x8*)&vtws[(size_t)(b * MM + et * 16 + lr) * MM + kf * 32 + lg * 8];
                acc = MFMA(af, bp[kf], acc);
            }
            int ig = m0 + lr;
            int e0 = et * 16 + lg * 4;
            uint2 pk;
            pk.x = pack2(acc[0], acc[1]);
            pk.y = pack2(acc[2], acc[3]);
            *(uint2*)&saws[(size_t)(b * MM + ig) * EE + e0] = pk;
        }
    }
    __syncthreads();
    __threadfence();
    if (tid == 0)
        __hip_atomic_fetch_add(flag2, 1, __ATOMIC_RELEASE, __HIP_MEMORY_SCOPE_AGENT);
    if (tid == 0) {
        int guard = 0;
        while (__hip_atomic_load(flag2, __ATOMIC_ACQUIRE, __HIP_MEMORY_SCOPE_AGENT) < 8
               && guard < 100000000) { __builtin_amdgcn_s_sleep(2); ++guard; }
    }
    __syncthreads();
    __threadfence();

    // ---- Stage 3: final for candidate chunk c (l = m0..m0+15) ----
    {
        int p = posneg[b * MM + m0 + lr];
        bf16x8 caf[4];
#pragma unroll
        for (int kf = 0; kf < 4; ++kf)
            caf[kf] = load_w_frag(emb_loc + (size_t)p * 128 + kf * 32 + lg * 8);
        float vout[4] = {0.f, 0.f, 0.f, 0.f};
#pragma unroll
        for (int t2 = 0; t2 < 2; ++t2) {
            int mt = 2 * w + t2;
            f32x4 acc = (f32x4){0.f, 0.f, 0.f, 0.f};
#pragma unroll
            for (int kf = 0; kf < 4; ++kf) {
                bf16x8 bf = *(const bf16x8*)&saws[(size_t)(b * MM + mt * 16 + lr) * EE + kf * 32 + lg * 8];
                acc = MFMA(caf[kf], bf, acc);
            }
            int m = mt * 16 + lr;
            float wt = tms[m], wb = bsv[m];
            float4 m2 = *(const float4*)&mat2[(size_t)(b * MM + m) * MM + m0 + lg * 4];
            vout[0] += acc[0] * (wt + wb * m2.x);
            vout[1] += acc[1] * (wt + wb * m2.y);
            vout[2] += acc[2] * (wt + wb * m2.z);
            vout[3] += acc[3] * (wt + wb * m2.w);
        }
#pragma unroll
        for (int r = 0; r < 4; ++r) {
            float v = vout[r];
            v += __shfl_xor(v, 1, 64);
            v += __shfl_xor(v, 2, 64);
            v += __shfl_xor(v, 4, 64);
            v += __shfl_xor(v, 8, 64);
            if (lr == 0) PART[w][lg * 4 + r] = v;
        }
    }
    __syncthreads();
    if (tid < 16)
        outp[b * MM + m0 + tid] = PART[0][tid] + PART[1][tid] + PART[2][tid] + PART[3][tid];
}

extern "C" void kernel_launch(void* const* d_in, const int* in_sizes, int n_in,
                              void* d_out, int out_size, void* d_ws, size_t ws_size,
                              hipStream_t stream) {
    const int* full_seq = (const int*)d_in[0];
    const int* time_seq = (const int*)d_in[1];
    const int* user     = (const int*)d_in[2];
    const int* posneg   = (const int*)d_in[3];
    const int* traj_len = (const int*)d_in[4];
    const float* mat1   = (const float*)d_in[5];
    const float* mat2   = (const float*)d_in[6];
    const float* vec    = (const float*)d_in[7];
    const float* emb_t  = (const float*)d_in[8];
    const float* emb_u  = (const float*)d_in[9];
    const float* emb_loc= (const float*)d_in[10];
    const float* emb_sl = (const float*)d_in[11];
    const float* emb_su = (const float*)d_in[12];
    const float* emb_tl = (const float*)d_in[13];
    const float* emb_tu = (const float*)d_in[14];
    const float* Wq     = (const float*)d_in[15];
    const float* Wk     = (const float*)d_in[16];
    const float* Wv     = (const float*)d_in[17];

    short* ws = (short*)d_ws;
    int* flags = (int*)(ws + WS_FLAGS_OFF);

    hipMemsetAsync(flags, 0, 2 * NB * FLAG_STRIDE * sizeof(int), stream);
    k_all<<<dim3(8, 32), 256, 0, stream>>>(full_seq, time_seq, user, posneg, traj_len,
                                           mat1, mat2, vec, emb_t, emb_u, emb_loc,
                                           emb_sl, emb_su, emb_tl, emb_tu,
                                           Wq, Wk, Wv, ws, flags, (float*)d_out);
}

// Round 10
// 26.508 us; speedup vs baseline: 4.4804x; 4.4804x over previous
//
#include <hip/hip_runtime.h>
#include <hip/hip_bf16.h>

#define HOURS 24
#define NB 32
#define MM 128
#define EE 128

typedef short bf16x8 __attribute__((ext_vector_type(8)));
typedef float f32x4 __attribute__((ext_vector_type(4)));

__device__ __forceinline__ unsigned short f2bfu(float f) {
    __hip_bfloat16 h = __float2bfloat16(f);
    return __builtin_bit_cast(unsigned short, h);
}
__device__ __forceinline__ unsigned int pack2(float a, float b) {
    return (unsigned int)f2bfu(a) | ((unsigned int)f2bfu(b) << 16);
}
// swizzled short-index of 16B unit `unit` in row `row` of a [*][128] bf16 tile
__device__ __forceinline__ int swz8(int row, int unit) {
    return row * 128 + (((unit ^ (row & 7)) & 15) << 3);
}
// load 8 consecutive f32 from global, convert to bf16x8 fragment
__device__ __forceinline__ bf16x8 load_w_frag(const float* base) {
    float4 x = *(const float4*)base;
    float4 y = *(const float4*)(base + 4);
    union { unsigned int u[4]; bf16x8 v; } r;
    r.u[0] = pack2(x.x, x.y); r.u[1] = pack2(x.z, x.w);
    r.u[2] = pack2(y.x, y.y); r.u[3] = pack2(y.z, y.w);
    return r.v;
}

#define MFMA(a, b, c) __builtin_amdgcn_mfma_f32_16x16x32_bf16(a, b, c, 0, 0, 0)

// ---------------- Kernel 1: joint gather + Q/K/VT; all loads issued at entry --------
__global__ __launch_bounds__(256) void k_qkv(
    const int* __restrict__ time_seq, const int* __restrict__ full_seq,
    const int* __restrict__ user,
    const float* __restrict__ emb_t, const float* __restrict__ emb_u,
    const float* __restrict__ emb_loc,
    const float* __restrict__ Wq, const float* __restrict__ Wk, const float* __restrict__ Wv,
    short* __restrict__ qws, short* __restrict__ kws, short* __restrict__ vtws)
{
    __shared__ alignas(16) short Jl[64 * 128];   // 16KB
    int b = blockIdx.y;
    int which = blockIdx.x >> 1;
    int half = blockIdx.x & 1;
    int m0 = half * 64;
    int tid = threadIdx.x;
    int l = tid & 63, w = tid >> 6;
    int lr = l & 15, lg = l >> 4;

    // ---- entry: J gather indices (dependent-chain roots) ----
    int uid = user[b];
    int tt[8], llx[8];
#pragma unroll
    for (int it = 0; it < 8; ++it) {
        int i4 = it * 256 + tid;
        int mm = i4 >> 5;
        tt[it]  = time_seq[b * MM + m0 + mm];
        llx[it] = full_seq[b * MM + m0 + mm];
    }
    // ---- entry: W fragments (same pattern for all three W's) ----
    const float* W = (which == 0) ? Wq : (which == 1) ? Wk : Wv;
    bf16x8 wf[2][4];
#pragma unroll
    for (int nt = 0; nt < 2; ++nt) {
        int n = (2 * w + nt) * 16 + lr;
#pragma unroll
        for (int kf = 0; kf < 4; ++kf)
            wf[nt][kf] = load_w_frag(W + (size_t)n * 128 + kf * 32 + lg * 8);
    }
    // ---- J staging (gather-sum f32 -> bf16, swizzled) ----
    const float4* Eu4 = (const float4*)(emb_u + (size_t)uid * 128);
#pragma unroll
    for (int it = 0; it < 8; ++it) {
        int i4 = it * 256 + tid;
        int mm = i4 >> 5;
        int fq = i4 & 31;
        int tim = (tt[it] - 1) % HOURS + 1;
        float4 a = ((const float4*)(emb_t + (size_t)tim * 128))[fq];
        float4 c = ((const float4*)(emb_loc + (size_t)llx[it] * 128))[fq];
        float4 u = Eu4[fq];
        uint2 pk;
        pk.x = pack2(a.x + c.x + u.x, a.y + c.y + u.y);
        pk.y = pack2(a.z + c.z + u.z, a.w + c.w + u.w);
        *(uint2*)&Jl[swz8(mm, fq >> 1) + (fq & 1) * 4] = pk;
    }
    __syncthreads();

    if (which < 2) {
        short* outp = which ? kws : qws;
        f32x4 acc[2][4];
#pragma unroll
        for (int nt = 0; nt < 2; ++nt)
#pragma unroll
            for (int mt = 0; mt < 4; ++mt) acc[nt][mt] = (f32x4){0.f, 0.f, 0.f, 0.f};
#pragma unroll
        for (int mt = 0; mt < 4; ++mt) {
            bf16x8 bf[4];
#pragma unroll
            for (int kf = 0; kf < 4; ++kf)
                bf[kf] = *(const bf16x8*)&Jl[swz8(mt * 16 + lr, kf * 4 + lg)];
#pragma unroll
            for (int nt = 0; nt < 2; ++nt)
#pragma unroll
                for (int kf = 0; kf < 4; ++kf)
                    acc[nt][mt] = MFMA(wf[nt][kf], bf[kf], acc[nt][mt]);
        }
#pragma unroll
        for (int nt = 0; nt < 2; ++nt)
#pragma unroll
            for (int mt = 0; mt < 4; ++mt) {
                int mg = m0 + mt * 16 + lr;
                int n0 = (2 * w + nt) * 16 + lg * 4;
                uint2 pk;
                pk.x = pack2(acc[nt][mt][0], acc[nt][mt][1]);
                pk.y = pack2(acc[nt][mt][2], acc[nt][mt][3]);
                *(uint2*)&outp[(size_t)(b * MM + mg) * EE + n0] = pk;
            }
    } else {
        f32x4 acc[4][2];
#pragma unroll
        for (int mt = 0; mt < 4; ++mt)
#pragma unroll
            for (int nt = 0; nt < 2; ++nt) acc[mt][nt] = (f32x4){0.f, 0.f, 0.f, 0.f};
#pragma unroll
        for (int mt = 0; mt < 4; ++mt) {
            bf16x8 af[4];
#pragma unroll
            for (int kf = 0; kf < 4; ++kf)
                af[kf] = *(const bf16x8*)&Jl[swz8(mt * 16 + lr, kf * 4 + lg)];
#pragma unroll
            for (int nt = 0; nt < 2; ++nt)
#pragma unroll
                for (int kf = 0; kf < 4; ++kf)
                    acc[mt][nt] = MFMA(af[kf], wf[nt][kf], acc[mt][nt]);
        }
#pragma unroll
        for (int mt = 0; mt < 4; ++mt)
#pragma unroll
            for (int nt = 0; nt < 2; ++nt) {
                int ng = (2 * w + nt) * 16 + lr;
                int mp = m0 + mt * 16 + lg * 4;
                uint2 pk;
                pk.x = pack2(acc[mt][nt][0], acc[mt][nt][1]);
                pk.y = pack2(acc[mt][nt][2], acc[mt][nt][3]);
                *(uint2*)&vtws[(size_t)(b * MM + ng) * MM + mp] = pk;
            }
    }
}

// ---------------- Kernel 2: attention; ALL global operands prefetched at entry ------
__global__ __launch_bounds__(256) void k_attn(
    const short* __restrict__ qws, const short* __restrict__ kws,
    const short* __restrict__ vtws,
    const float* __restrict__ mat1, const int* __restrict__ traj_len,
    const float* __restrict__ esl, const float* __restrict__ esu,
    const float* __restrict__ etl, const float* __restrict__ etu,
    short* __restrict__ saws)
{
    __shared__ alignas(16) float Sf[16 * 132];   // 8448B
    __shared__ alignas(16) short Pl[16 * 128];   // 4KB
    __shared__ float coef[8];

    int b = blockIdx.y;
    int i0 = blockIdx.x * 16;
    int tid = threadIdx.x;
    int l = tid & 63, w = tid >> 6;
    int lr = l & 15, lg = l >> 4;
    int tl = traj_len[b];

    // ---- entry prefetch: mat1 operands for THIS thread's softmax slice ----
    int r16 = tid >> 4, u16 = tid & 15;
    const float4* m14 = (const float4*)(mat1 + ((size_t)(b * MM + i0 + r16) * MM + u16 * 8) * 2);
    float4 d0 = m14[0], d1 = m14[1], d2 = m14[2], d3 = m14[3];
    // ---- entry prefetch: Q, K, VT fragments ----
    bf16x8 qf[4], bk[2][4], av[2][4];
#pragma unroll
    for (int kf = 0; kf < 4; ++kf)
        qf[kf] = *(const bf16x8*)&qws[(size_t)(b * MM + i0 + lr) * EE + kf * 32 + lg * 8];
#pragma unroll
    for (int t2 = 0; t2 < 2; ++t2) {
        int rt = (2 * w + t2) * 16 + lr;
#pragma unroll
        for (int kf = 0; kf < 4; ++kf) {
            bk[t2][kf] = *(const bf16x8*)&kws[(size_t)(b * MM + rt) * EE + kf * 32 + lg * 8];
            av[t2][kf] = *(const bf16x8*)&vtws[(size_t)(b * MM + rt) * MM + kf * 32 + lg * 8];
        }
    }
    // ---- coefs: wave w computes table sums 2w, 2w+1 ----
    {
        const float* tb[4] = {esl, esu, etl, etu};
#pragma unroll
        for (int s = 0; s < 2; ++s) {
            int c = 2 * w + s;
            const float* t = tb[c >> 1];
            float v = t[(c & 1) * 128 + l] + t[(c & 1) * 128 + 64 + l];
#pragma unroll
            for (int off = 32; off >= 1; off >>= 1) v += __shfl_xor(v, off, 64);
            if (l == 0) coef[c] = v;
        }
    }

    // ---- QK^T: wave w covers j-tiles {2w, 2w+1} ----
#pragma unroll
    for (int t2 = 0; t2 < 2; ++t2) {
        int jt = 2 * w + t2;
        f32x4 acc = (f32x4){0.f, 0.f, 0.f, 0.f};
#pragma unroll
        for (int kf = 0; kf < 4; ++kf) acc = MFMA(qf[kf], bk[t2][kf], acc);
#pragma unroll
        for (int r = 0; r < 4; ++r)
            Sf[(lg * 4 + r) * 132 + jt * 16 + lr] = acc[r];
    }
    __syncthreads();

    // ---- softmax: thread (r16, u16) uses its prefetched mat1 regs ----
    {
        int j0 = u16 * 8;
        int i = i0 + r16;
        int mi = (i < tl) ? 1 : 0;
        float c0_1 = coef[1] + coef[5];
        float c1_1 = (coef[3] - coef[1]) * 0.01f;
        float c2_1 = (coef[7] - coef[5]) * 0.01f;
        float c0_0 = coef[0] + coef[4];
        float c1_0 = (coef[2] - coef[0]) * 0.01f;
        float c2_0 = (coef[6] - coef[4]) * 0.01f;
        const float* sb = &Sf[r16 * 132 + j0];
        float4 s01 = *(const float4*)sb;
        float4 s23 = *(const float4*)(sb + 4);
        float sv[8] = {s01.x, s01.y, s01.z, s01.w, s23.x, s23.y, s23.z, s23.w};
        float ds[8] = {d0.x, d0.z, d1.x, d1.z, d2.x, d2.z, d3.x, d3.z};
        float dt[8] = {d0.y, d0.w, d1.y, d1.w, d2.y, d2.w, d3.y, d3.w};
        float lgv[8];
        int mk[8];
#pragma unroll
        for (int jj = 0; jj < 8; ++jj) {
            int j = j0 + jj;
            mk[jj] = mi & ((j < tl) ? 1 : 0);
            float cc0 = mk[jj] ? c0_1 : c0_0;
            float cc1 = mk[jj] ? c1_1 : c1_0;
            float cc2 = mk[jj] ? c2_1 : c2_0;
            lgv[jj] = sv[jj] + cc0 + cc1 * ds[jj] + cc2 * dt[jj];
        }
        float mx = lgv[0];
#pragma unroll
        for (int jj = 1; jj < 8; ++jj) mx = fmaxf(mx, lgv[jj]);
#pragma unroll
        for (int off = 8; off >= 1; off >>= 1) mx = fmaxf(mx, __shfl_xor(mx, off, 64));
        float ee[8], sum = 0.f;
#pragma unroll
        for (int jj = 0; jj < 8; ++jj) { ee[jj] = __expf(lgv[jj] - mx); sum += ee[jj]; }
#pragma unroll
        for (int off = 8; off >= 1; off >>= 1) sum += __shfl_xor(sum, off, 64);
        float inv = 1.0f / sum;
        uint4 pk;
        pk.x = pack2(ee[0] * inv * mk[0], ee[1] * inv * mk[1]);
        pk.y = pack2(ee[2] * inv * mk[2], ee[3] * inv * mk[3]);
        pk.z = pack2(ee[4] * inv * mk[4], ee[5] * inv * mk[5]);
        pk.w = pack2(ee[6] * inv * mk[6], ee[7] * inv * mk[7]);
        *(uint4*)&Pl[swz8(r16, u16)] = pk;
    }
    __syncthreads();

    // ---- PV with prefetched VT frags ----
    bf16x8 bp[4];
#pragma unroll
    for (int kf = 0; kf < 4; ++kf)
        bp[kf] = *(const bf16x8*)&Pl[swz8(lr, kf * 4 + lg)];
#pragma unroll
    for (int t2 = 0; t2 < 2; ++t2) {
        int et = 2 * w + t2;
        f32x4 acc = (f32x4){0.f, 0.f, 0.f, 0.f};
#pragma unroll
        for (int kf = 0; kf < 4; ++kf) acc = MFMA(av[t2][kf], bp[kf], acc);
        int ig = i0 + lr;
        int e0 = et * 16 + lg * 4;
        uint2 pk;
        pk.x = pack2(acc[0], acc[1]);
        pk.y = pack2(acc[2], acc[3]);
        *(uint2*)&saws[(size_t)(b * MM + ig) * EE + e0] = pk;
    }
}

// ---------------- Kernel 3: final; all operands prefetched at entry ----------------
__global__ __launch_bounds__(256) void k_final(
    const short* __restrict__ saws, const int* __restrict__ posneg,
    const float* __restrict__ emb_loc, const float* __restrict__ mat2,
    const float* __restrict__ vecg, const int* __restrict__ traj_len,
    const float* __restrict__ esl, const float* __restrict__ esu,
    const float* __restrict__ etl, const float* __restrict__ etu,
    float* __restrict__ outp)
{
    __shared__ float coef[8];
    __shared__ float tms[128], bsv[128];
    __shared__ float PART[4][16];

    int b = blockIdx.y;
    int l0 = blockIdx.x * 16;
    int tid = threadIdx.x;
    int l = tid & 63, w = tid >> 6;
    int lr = l & 15, lg = l >> 4;
    int tl = traj_len[b];

    // ---- entry prefetch: cand chain, sa frags, mat2, vec ----
    int p = posneg[b * MM + l0 + lr];
    bf16x8 caf[4];
#pragma unroll
    for (int kf = 0; kf < 4; ++kf)
        caf[kf] = load_w_frag(emb_loc + (size_t)p * 128 + kf * 32 + lg * 8);
    bf16x8 bsa[2][4];
    float4 m2[2];
#pragma unroll
    for (int t2 = 0; t2 < 2; ++t2) {
        int m = (2 * w + t2) * 16 + lr;
#pragma unroll
        for (int kf = 0; kf < 4; ++kf)
            bsa[t2][kf] = *(const bf16x8*)&saws[(size_t)(b * MM + m) * EE + kf * 32 + lg * 8];
        m2[t2] = *(const float4*)&mat2[(size_t)(b * MM + m) * MM + l0 + lg * 4];
    }
    float vg = (tid < 128) ? vecg[b * MM + tid] : 0.f;

    // ---- coefs ----
    {
        const float* tb[4] = {esl, esu, etl, etu};
#pragma unroll
        for (int s = 0; s < 2; ++s) {
            int c = 2 * w + s;
            const float* t = tb[c >> 1];
            float v = t[(c & 1) * 128 + l] + t[(c & 1) * 128 + 64 + l];
#pragma unroll
            for (int off = 32; off >= 1; off >>= 1) v += __shfl_xor(v, off, 64);
            if (l == 0) coef[c] = v;
        }
    }
    __syncthreads();
    if (tid < 128) {
        int vv = (tid < tl) ? 1 : 0;
        float ssl = vv ? coef[1] : coef[0];
        float ssu = vv ? coef[3] : coef[2];
        float stl = vv ? coef[5] : coef[4];
        float stu = vv ? coef[7] : coef[6];
        tms[tid] = ssl + stl + (stu - stl) * 0.01f * vg;
        bsv[tid] = (ssu - ssl) * 0.01f;
    }
    __syncthreads();

    // ---- G = cand . sa^T (wave w -> m-tiles {2w,2w+1}) + epilogue ----
    float vout[4] = {0.f, 0.f, 0.f, 0.f};
#pragma unroll
    for (int t2 = 0; t2 < 2; ++t2) {
        f32x4 acc = (f32x4){0.f, 0.f, 0.f, 0.f};
#pragma unroll
        for (int kf = 0; kf < 4; ++kf) acc = MFMA(caf[kf], bsa[t2][kf], acc);
        int m = (2 * w + t2) * 16 + lr;
        float wt = tms[m], wb = bsv[m];
        vout[0] += acc[0] * (wt + wb * m2[t2].x);
        vout[1] += acc[1] * (wt + wb * m2[t2].y);
        vout[2] += acc[2] * (wt + wb * m2[t2].z);
        vout[3] += acc[3] * (wt + wb * m2[t2].w);
    }
#pragma unroll
    for (int r = 0; r < 4; ++r) {
        float v = vout[r];
        v += __shfl_xor(v, 1, 64);
        v += __shfl_xor(v, 2, 64);
        v += __shfl_xor(v, 4, 64);
        v += __shfl_xor(v, 8, 64);
        if (lr == 0) PART[w][lg * 4 + r] = v;
    }
    __syncthreads();
    if (tid < 16)
        outp[b * MM + l0 + tid] = PART[0][tid] + PART[1][tid] + PART[2][tid] + PART[3][tid];
}

extern "C" void kernel_launch(void* const* d_in, const int* in_sizes, int n_in,
                              void* d_out, int out_size, void* d_ws, size_t ws_size,
                              hipStream_t stream) {
    const int* full_seq = (const int*)d_in[0];
    const int* time_seq = (const int*)d_in[1];
    const int* user     = (const int*)d_in[2];
    const int* posneg   = (const int*)d_in[3];
    const int* traj_len = (const int*)d_in[4];
    const float* mat1   = (const float*)d_in[5];
    const float* mat2   = (const float*)d_in[6];
    const float* vec    = (const float*)d_in[7];
    const float* emb_t  = (const float*)d_in[8];
    const float* emb_u  = (const float*)d_in[9];
    const float* emb_loc= (const float*)d_in[10];
    const float* emb_sl = (const float*)d_in[11];
    const float* emb_su = (const float*)d_in[12];
    const float* emb_tl = (const float*)d_in[13];
    const float* emb_tu = (const float*)d_in[14];
    const float* Wq     = (const float*)d_in[15];
    const float* Wk     = (const float*)d_in[16];
    const float* Wv     = (const float*)d_in[17];

    short* qws  = (short*)d_ws;
    short* kws  = qws + (size_t)NB * MM * EE;
    short* vtws = kws + (size_t)NB * MM * EE;
    short* saws = vtws + (size_t)NB * MM * EE;

    k_qkv<<<dim3(6, 32), 256, 0, stream>>>(time_seq, full_seq, user,
                                           emb_t, emb_u, emb_loc,
                                           Wq, Wk, Wv, qws, kws, vtws);
    k_attn<<<dim3(8, 32), 256, 0, stream>>>(qws, kws, vtws, mat1, traj_len,
                                            emb_sl, emb_su, emb_tl, emb_tu, saws);
    k_final<<<dim3(8, 32), 256, 0, stream>>>(saws, posneg, emb_loc, mat2, vec,
                                             traj_len, emb_sl, emb_su, emb_tl, emb_tu,
                                             (float*)d_out);
}